// Round 2
// baseline (296.324 us; speedup 1.0000x reference)
//
#include <hip/hip_runtime.h>
#include <hip/hip_bf16.h>

#define B_ 64
#define J_ 2048
#define K_ 32
#define D_ 16
#define KD 512
#define JG 128          // number of j-groups (spart partial chunks)
#define JC 16           // j's per group (2048/128)
#define BG 16           // b's per block

__device__ __forceinline__ float bf2f(unsigned int bits16) {
  unsigned int u = bits16 << 16;
  return __builtin_bit_cast(float, u);
}
__device__ __forceinline__ unsigned short f2bf(float f) {
  unsigned int u = __builtin_bit_cast(unsigned int, f);
  u = u + 0x7fffu + ((u >> 16) & 1u);   // round-to-nearest-even
  return (unsigned short)(u >> 16);
}

// ---------------- fused sweep: recompute u_hat tile in LDS, route, emit s-partials.
// grid (JG, 4 b-groups), 512 threads.
// MODE 0: c = 1/32, pass-1 only. MODE 1: logits = osum.u. MODE 2: + write c to out.
template <int MODE>
__global__ __launch_bounds__(512) void k_sweep(const float* __restrict__ inp,
                                               const float* __restrict__ W,
                                               const float* __restrict__ osum,
                                               float* __restrict__ spart,
                                               float* __restrict__ outp) {
  const int jg = blockIdx.x;
  const int b0 = blockIdx.y * BG;
  const int t = threadIdx.x;             // 0..511 ; kd = t (k = t>>4, d = t&15)
  const int lane = t & 63, wave = t >> 6;

  __shared__ float in_lds[BG][JC][16];                              // 16 KB
  __shared__ unsigned short u_lds[(MODE >= 1) ? BG * KD : 64];      // 16 KB bf16
  __shared__ float cbuf[(MODE == 2) ? BG * K_ * (JC + 1) : 4];      // 34.8 KB padded

  // stage inputs for the whole (b-tile, j-chunk): coalesced, matches global layout
  for (int e = t; e < BG * JC * 16; e += 512) {
    int b = e >> 8, rem = e & 255;
    in_lds[b][rem >> 4][rem & 15] =
        inp[((size_t)(b0 + b) * J_ + jg * JC + (rem >> 4)) * 16 + (rem & 15)];
  }

  float os[2][8];
  if constexpr (MODE >= 1) {
#pragma unroll
    for (int bb = 0; bb < 2; ++bb)
#pragma unroll
      for (int q = 0; q < 8; ++q)
        os[bb][q] = osum[(size_t)(b0 + 2 * wave + bb) * KD + 8 * lane + q];
  }

  float acc0[BG];       // MODE 0 accumulator (per-thread kd, all 16 b)
  float acc[2][8];      // MODE 1/2 accumulator (2 b per wave, 8 kd per lane)
#pragma unroll
  for (int b = 0; b < BG; ++b) acc0[b] = 0.f;
#pragma unroll
  for (int bb = 0; bb < 2; ++bb)
#pragma unroll
    for (int q = 0; q < 8; ++q) acc[bb][q] = 0.f;

  __syncthreads();

  // W[k,j,d,i] at (k*J_+j)*256 + d*16 + i : thread's 16 W floats are contiguous
  const float* wbase = W + (size_t)(t >> 4) * J_ * 256 + (size_t)(t & 15) * 16;
  const float4* wp = (const float4*)(wbase + (size_t)(jg * JC) * 256);
  float4 wa0 = wp[0], wa1 = wp[1], wa2 = wp[2], wa3 = wp[3];

  for (int jc = 0; jc < JC; ++jc) {
    // ---- pass 1: u[b][kd=t] for 16 b, W slice in regs, inputs via LDS broadcast
#pragma unroll 4
    for (int b = 0; b < BG; ++b) {
      const float4* xi = (const float4*)&in_lds[b][jc][0];
      float4 x0 = xi[0], x1 = xi[1], x2 = xi[2], x3 = xi[3];
      float a;
      a = x0.x * wa0.x;
      a = fmaf(x0.y, wa0.y, a); a = fmaf(x0.z, wa0.z, a); a = fmaf(x0.w, wa0.w, a);
      a = fmaf(x1.x, wa1.x, a); a = fmaf(x1.y, wa1.y, a);
      a = fmaf(x1.z, wa1.z, a); a = fmaf(x1.w, wa1.w, a);
      a = fmaf(x2.x, wa2.x, a); a = fmaf(x2.y, wa2.y, a);
      a = fmaf(x2.z, wa2.z, a); a = fmaf(x2.w, wa2.w, a);
      a = fmaf(x3.x, wa3.x, a); a = fmaf(x3.y, wa3.y, a);
      a = fmaf(x3.z, wa3.z, a); a = fmaf(x3.w, wa3.w, a);
      if constexpr (MODE == 0) acc0[b] += a;
      else u_lds[b * KD + t] = f2bf(a);
    }
    // prefetch next j's W before the barrier
    if (jc + 1 < JC) {
      const float4* wn = (const float4*)(wbase + (size_t)(jg * JC + jc + 1) * 256);
      wa0 = wn[0]; wa1 = wn[1]; wa2 = wn[2]; wa3 = wn[3];
    }

    if constexpr (MODE >= 1) {
      __syncthreads();
      // ---- pass 2: wave handles b = 2*wave + {0,1}; lane owns kd0 = 8*lane
#pragma unroll
      for (int bb = 0; bb < 2; ++bb) {
        const int bl = 2 * wave + bb;
        const uint4* ur = (const uint4*)(u_lds + bl * KD);
        uint4 cur = ur[lane];                       // contiguous 1KB per wave: conflict-free
        float u[8];
        u[0] = bf2f(cur.x & 0xffffu); u[1] = bf2f(cur.x >> 16);
        u[2] = bf2f(cur.y & 0xffffu); u[3] = bf2f(cur.y >> 16);
        u[4] = bf2f(cur.z & 0xffffu); u[5] = bf2f(cur.z >> 16);
        u[6] = bf2f(cur.w & 0xffffu); u[7] = bf2f(cur.w >> 16);
        float p = 0.f;
#pragma unroll
        for (int q = 0; q < 8; ++q) p = fmaf(os[bb][q], u[q], p);
        p += __shfl_xor(p, 1);                      // full dot for k = lane>>1
        float m = p;
#pragma unroll
        for (int s = 2; s <= 32; s <<= 1) m = fmaxf(m, __shfl_xor(m, s));
        float e = __expf(p - m);
        float S = e;
#pragma unroll
        for (int s = 2; s <= 32; s <<= 1) S += __shfl_xor(S, s);
        float c = e / S;
        if constexpr (MODE == 2) {
          if ((lane & 1) == 0) cbuf[(bl * K_ + (lane >> 1)) * (JC + 1) + jc] = c;
        }
#pragma unroll
        for (int q = 0; q < 8; ++q) acc[bb][q] = fmaf(c, u[q], acc[bb][q]);
      }
      __syncthreads();
    }
  }

  // ---- epilogue: s-partials
  if constexpr (MODE == 0) {
#pragma unroll
    for (int b = 0; b < BG; ++b)
      spart[((size_t)(b0 + b) * JG + jg) * KD + t] = acc0[b] * (1.0f / 32.0f);
  } else {
#pragma unroll
    for (int bb = 0; bb < 2; ++bb)
#pragma unroll
      for (int q = 0; q < 8; ++q)
        spart[((size_t)(b0 + 2 * wave + bb) * JG + jg) * KD + 8 * lane + q] = acc[bb][q];
  }

  if constexpr (MODE == 2) {
    __syncthreads();
    // flush c: thread t owns row (b = t>>5, k = t&31); 16 j's contiguous in out
    float* orow = outp + ((size_t)(b0 + (t >> 5)) * K_ + (t & 31)) * 2064 + 16 + jg * JC;
    const float* crow = &cbuf[t * (JC + 1)];
#pragma unroll
    for (int m4 = 0; m4 < 4; ++m4) {
      float4 v = make_float4(crow[4 * m4], crow[4 * m4 + 1], crow[4 * m4 + 2], crow[4 * m4 + 3]);
      *(float4*)(orow + 4 * m4) = v;
    }
  }
}

// ---------------- SQ: reduce partials -> s, squash -> outputs; accumulate osum.
// one wave per (b,k). lane: d = lane&15, partial-group pg = lane>>4.
__global__ __launch_bounds__(256) void k_squash(const float* __restrict__ spart,
                                                float* __restrict__ osum,
                                                float* __restrict__ outp,
                                                int first, int final_) {
  const int t = threadIdx.x;
  const int wave = t >> 6, lane = t & 63;
  const int gw = blockIdx.x * 4 + wave;   // 0..B_*K_-1
  const int b = gw >> 5, k = gw & 31;
  const int d = lane & 15, pg = lane >> 4;
  float s = 0.f;
  for (int p = pg; p < JG; p += 4)
    s += spart[((size_t)b * JG + p) * KD + k * D_ + d];
  s += __shfl_xor(s, 16);
  s += __shfl_xor(s, 32);
  float ss = s * s;
  ss += __shfl_xor(ss, 1); ss += __shfl_xor(ss, 2);
  ss += __shfl_xor(ss, 4); ss += __shfl_xor(ss, 8);
  float scale = (ss / (1.f + ss)) * rsqrtf(ss + 1e-7f);
  float ov = scale * s;
  if (lane < 16) {
    if (final_) {
      outp[((size_t)b * K_ + k) * 2064 + d] = ov;
    } else {
      float prev = first ? 0.f : osum[(b * K_ + k) * D_ + d];
      osum[(b * K_ + k) * D_ + d] = prev + ov;
    }
  }
}

extern "C" void kernel_launch(void* const* d_in, const int* in_sizes, int n_in,
                              void* d_out, int out_size, void* d_ws, size_t ws_size,
                              hipStream_t stream) {
  const float* inp = (const float*)d_in[0];   // [64,2048,16]
  const float* W   = (const float*)d_in[1];   // [32,2048,16,16]
  float* outp = (float*)d_out;                // [64,32,2064]
  char* ws = (char*)d_ws;
  // ws layout: spart (16 MiB) | osum (128 KiB)
  float* spart = (float*)ws;
  float* osum  = (float*)(ws + (size_t)16777216);

  dim3 grid(JG, B_ / BG);
  k_sweep<0><<<grid, 512, 0, stream>>>(inp, W, nullptr, spart, nullptr);
  k_squash<<<B_ * K_ / 4, 256, 0, stream>>>(spart, osum, outp, 1, 0);
  k_sweep<1><<<grid, 512, 0, stream>>>(inp, W, osum, spart, nullptr);
  k_squash<<<B_ * K_ / 4, 256, 0, stream>>>(spart, osum, outp, 0, 0);
  k_sweep<2><<<grid, 512, 0, stream>>>(inp, W, osum, spart, outp);
  k_squash<<<B_ * K_ / 4, 256, 0, stream>>>(spart, osum, outp, 0, 1);
}

// Round 3
// 136.097 us; speedup vs baseline: 2.1773x; 2.1773x over previous
//
#include <hip/hip_runtime.h>
#include <hip/hip_bf16.h>

#define B_ 64
#define J_ 2048
#define K_ 32
#define D_ 16
#define KD 512
#define WPB 64            // waves per batch element in routing kernels
#define JCH (J_ / WPB)    // 32 j's per wave

typedef __attribute__((ext_vector_type(8))) short short8v;   // 8 bf16 (4 VGPR)
typedef __attribute__((ext_vector_type(4))) float f32x4;     // 4 f32 acc

__device__ __forceinline__ float bf2f(unsigned int bits16) {
  unsigned int u = bits16 << 16;
  return __builtin_bit_cast(float, u);
}
__device__ __forceinline__ unsigned short f2bf(float f) {
  unsigned int u = __builtin_bit_cast(unsigned int, f);
  u = u + 0x7fffu + ((u >> 16) & 1u);   // round-to-nearest-even
  return (unsigned short)(u >> 16);
}

// ---------------- K1 (MFMA): u_hat[b][j][kd] bf16 = sum_i inputs[b,j,i] * W[kd(j),i]
// One block per j, 4 waves. C'[kd,b]: Aop = W-slice (M=kd tiles), Bop = inputs^T (N=b).
// K=16 lives in frag slots 0-3 (i = 4*(lane>>4)+e); slots 4-7 zero. A and B use the
// same slot->k mapping, so the contraction is correct for any HW slot packing.
__global__ __launch_bounds__(256) void k_uhat(const float* __restrict__ inp,
                                              const float* __restrict__ W,
                                              unsigned int* __restrict__ uhat /* bf16x2 */) {
  const int j = blockIdx.x;
  const int t = threadIdx.x;
  const int wave = t >> 6, lane = t & 63;
  const int g = lane >> 4, r = lane & 15;

  __shared__ __align__(16) unsigned short u_lds[B_ * KD];   // 64 KB, XOR-swizzled

  // ---- A frags: 8 kd-tiles (wave's kd-chunk = 128 rows of W_j)
  short8v afr[8];
#pragma unroll
  for (int tile = 0; tile < 8; ++tile) {
    const int kd = wave * 128 + tile * 16 + r;              // W row (k = kd>>4, d = kd&15)
    const float4 wv = *(const float4*)(W + (size_t)(kd >> 4) * (J_ * 256) +
                                       (size_t)j * 256 + (kd & 15) * 16 + 4 * g);
    short8v f;
    f[0] = (short)f2bf(wv.x); f[1] = (short)f2bf(wv.y);
    f[2] = (short)f2bf(wv.z); f[3] = (short)f2bf(wv.w);
    f[4] = 0; f[5] = 0; f[6] = 0; f[7] = 0;
    afr[tile] = f;
  }
  // ---- B frags: 4 b-tiles (inputs^T)
  short8v bfr[4];
#pragma unroll
  for (int bt = 0; bt < 4; ++bt) {
    const int b = bt * 16 + r;
    const float4 xv = *(const float4*)(inp + ((size_t)b * J_ + j) * 16 + 4 * g);
    short8v f;
    f[0] = (short)f2bf(xv.x); f[1] = (short)f2bf(xv.y);
    f[2] = (short)f2bf(xv.z); f[3] = (short)f2bf(xv.w);
    f[4] = 0; f[5] = 0; f[6] = 0; f[7] = 0;
    bfr[bt] = f;
  }

  // ---- 32 MFMAs; pack each tile's 4 consecutive-kd outputs -> 8B LDS write
#pragma unroll
  for (int tile = 0; tile < 8; ++tile) {
#pragma unroll
    for (int bt = 0; bt < 4; ++bt) {
      f32x4 acc = __builtin_amdgcn_mfma_f32_16x16x32_bf16(
          afr[tile], bfr[bt], (f32x4){0.f, 0.f, 0.f, 0.f}, 0, 0, 0);
      const int b = bt * 16 + r;
      const int kd0 = wave * 128 + tile * 16 + g * 4;       // reg ri -> kd0+ri, col -> b
      const int kd8 = kd0 >> 3;
      const unsigned int lo = (unsigned int)f2bf(acc[0]) | ((unsigned int)f2bf(acc[1]) << 16);
      const unsigned int hi = (unsigned int)f2bf(acc[2]) | ((unsigned int)f2bf(acc[3]) << 16);
      unsigned short* p = &u_lds[b * KD + ((kd8 ^ (b & 7)) << 3) + (kd0 & 7)];
      *(uint2*)p = make_uint2(lo, hi);
    }
  }
  __syncthreads();

  // ---- coalesced store: wave streams one b-row (1 KB) per iteration
  uint4* __restrict__ up = (uint4*)uhat;
#pragma unroll
  for (int it = 0; it < 16; ++it) {
    const int idx = it * 256 + t;
    const int b = idx >> 6, kd8 = idx & 63;
    const uint4 v = *(const uint4*)&u_lds[b * KD + ((kd8 ^ (b & 7)) << 3)];
    up[((size_t)b * J_ + j) * 64 + kd8] = v;
  }
}

// ---------------- RK: one routing sweep over u_hat (round-1 proven, ~21us).
// wave = (b, j-chunk of 32). lane owns 8 contiguous (k,d): kd0 = lane*8, k = lane>>1.
template <int MODE>
__global__ __launch_bounds__(256) void k_route(const unsigned int* __restrict__ uhat,
                                               const float* __restrict__ osum,
                                               float* __restrict__ spart,
                                               float* __restrict__ outp) {
  const int t = threadIdx.x;
  const int wave = t >> 6, lane = t & 63;
  const int gw = blockIdx.x * 4 + wave;       // 0 .. B_*WPB-1
  const int b = gw / WPB;
  const int lw = gw % WPB;
  const int kd0 = lane * 8;
  const int k = lane >> 1;

  __shared__ float cbuf[(MODE == 2) ? 4 * K_ * (JCH + 1) : 4];

  float os[8];
  if constexpr (MODE >= 1) {
#pragma unroll
    for (int q = 0; q < 8; ++q) os[q] = osum[b * KD + kd0 + q];
  }
  float acc[8] = {0.f, 0.f, 0.f, 0.f, 0.f, 0.f, 0.f, 0.f};

  const int j0 = lw * JCH;
  const uint4* up = reinterpret_cast<const uint4*>(uhat) + (size_t)(b * J_ + j0) * 64 + lane;
  uint4 nxt = *up;                            // 16B/lane, wave reads 1KB contiguous
  for (int jj = 0; jj < JCH; ++jj) {
    uint4 cur = nxt;
    if (jj + 1 < JCH) nxt = up[(size_t)(jj + 1) * 64];
    float u[8];
    u[0] = bf2f(cur.x & 0xffffu); u[1] = bf2f(cur.x >> 16);
    u[2] = bf2f(cur.y & 0xffffu); u[3] = bf2f(cur.y >> 16);
    u[4] = bf2f(cur.z & 0xffffu); u[5] = bf2f(cur.z >> 16);
    u[6] = bf2f(cur.w & 0xffffu); u[7] = bf2f(cur.w >> 16);

    float c;
    if constexpr (MODE == 0) {
      c = 1.0f / 32.0f;
    } else {
      float p = 0.f;
#pragma unroll
      for (int q = 0; q < 8; ++q) p = fmaf(os[q], u[q], p);
      p += __shfl_xor(p, 1);                  // lane pair -> full dot for k = lane>>1
      float m = p;
#pragma unroll
      for (int s = 2; s <= 32; s <<= 1) m = fmaxf(m, __shfl_xor(m, s));
      float e = __expf(p - m);
      float S = e;
#pragma unroll
      for (int s = 2; s <= 32; s <<= 1) S += __shfl_xor(S, s);
      c = e / S;
    }
    if constexpr (MODE == 2) {
      if ((lane & 1) == 0) cbuf[wave * (K_ * (JCH + 1)) + k * (JCH + 1) + jj] = c;
    }
#pragma unroll
    for (int q = 0; q < 8; ++q) acc[q] = fmaf(c, u[q], acc[q]);
  }

  if constexpr (MODE == 2) {
    __syncthreads();
    // write c rows: K_=32 rows x JCH=32 cols per wave; 2 rows per pass
    const int col = lane & 31, rhalf = lane >> 5;
#pragma unroll
    for (int pass = 0; pass < 16; ++pass) {
      int rr = pass * 2 + rhalf;
      outp[(size_t)(b * K_ + rr) * 2064 + 16 + j0 + col] =
          cbuf[wave * (K_ * (JCH + 1)) + rr * (JCH + 1) + col];
    }
  }

#pragma unroll
  for (int q = 0; q < 8; ++q)
    spart[(size_t)(b * WPB + lw) * KD + kd0 + q] = acc[q];
}

// ---------------- SQ: reduce partials -> s, squash -> outputs; accumulate osum.
__global__ __launch_bounds__(256) void k_squash(const float* __restrict__ spart,
                                                float* __restrict__ osum,
                                                float* __restrict__ outp,
                                                int first, int final_) {
  const int t = threadIdx.x;
  const int wave = t >> 6, lane = t & 63;
  const int gw = blockIdx.x * 4 + wave;   // 0..B_*K_-1
  const int b = gw >> 5, k = gw & 31;
  const int d = lane & 15, pg = lane >> 4;
  float s = 0.f;
  for (int p = pg; p < WPB; p += 4)
    s += spart[(size_t)(b * WPB + p) * KD + k * D_ + d];
  s += __shfl_xor(s, 16);
  s += __shfl_xor(s, 32);
  float ss = s * s;
  ss += __shfl_xor(ss, 1); ss += __shfl_xor(ss, 2);
  ss += __shfl_xor(ss, 4); ss += __shfl_xor(ss, 8);
  float scale = (ss / (1.f + ss)) * rsqrtf(ss + 1e-7f);
  float ov = scale * s;
  if (lane < 16) {
    if (final_) {
      outp[(size_t)(b * K_ + k) * 2064 + d] = ov;
    } else {
      float prev = first ? 0.f : osum[(b * K_ + k) * D_ + d];
      osum[(b * K_ + k) * D_ + d] = prev + ov;
    }
  }
}

extern "C" void kernel_launch(void* const* d_in, const int* in_sizes, int n_in,
                              void* d_out, int out_size, void* d_ws, size_t ws_size,
                              hipStream_t stream) {
  const float* inp = (const float*)d_in[0];   // [64,2048,16]
  const float* W   = (const float*)d_in[1];   // [32,2048,16,16]
  float* outp = (float*)d_out;                // [64,32,2064]
  char* ws = (char*)d_ws;
  // ws layout: uhat bf16 (128 MiB) | spart (8 MiB) | osum (128 KiB)
  unsigned int* uhat = (unsigned int*)ws;
  float* spart = (float*)(ws + (size_t)134217728);
  float* osum  = (float*)(ws + (size_t)134217728 + 8388608);

  k_uhat<<<J_, 256, 0, stream>>>(inp, W, uhat);
  k_route<0><<<B_ * WPB / 4, 256, 0, stream>>>(uhat, nullptr, spart, nullptr);
  k_squash<<<B_ * K_ / 4, 256, 0, stream>>>(spart, osum, outp, 1, 0);
  k_route<1><<<B_ * WPB / 4, 256, 0, stream>>>(uhat, osum, spart, nullptr);
  k_squash<<<B_ * K_ / 4, 256, 0, stream>>>(spart, osum, outp, 0, 0);
  k_route<2><<<B_ * WPB / 4, 256, 0, stream>>>(uhat, osum, spart, outp);
  k_squash<<<B_ * K_ / 4, 256, 0, stream>>>(spart, osum, outp, 0, 1);
}